// Round 7
// baseline (209.160 us; speedup 1.0000x reference)
//
#include <hip/hip_runtime.h>
#include <hip/hip_bf16.h>
#include <cmath>

using bf16 = __hip_bfloat16;
typedef __attribute__((ext_vector_type(4))) float  f32x4;
typedef __attribute__((ext_vector_type(8))) short  bf16x8;
typedef unsigned int u32;
typedef unsigned short u16;

// async global->LDS, 16B per lane
__device__ __forceinline__ void gl_lds16(const bf16* g, bf16* l) {
    __builtin_amdgcn_global_load_lds(
        (const __attribute__((address_space(1))) u32*)g,
        (__attribute__((address_space(3))) u32*)l, 16, 0, 0);
}
__device__ __forceinline__ u32 pk2(float a, float b) {
    bf16 ha = __float2bfloat16(a), hb = __float2bfloat16(b);
    return (u32)*(u16*)&ha | ((u32)*(u16*)&hb << 16);
}
__device__ __forceinline__ float b2f(u16 v) {
    return __uint_as_float((u32)v << 16);
}

// ---------------------------------------------------------------------------
// weights -> bf16: [Wq | Wk | Wv | Wffn]
// ---------------------------------------------------------------------------
__global__ __launch_bounds__(256) void wconv(
    const float* __restrict__ a, const float* __restrict__ b,
    const float* __restrict__ c, const float* __restrict__ d,
    bf16* __restrict__ o)
{
    int i = blockIdx.x * 256 + threadIdx.x;
    int which = i >> 16, off = i & 65535;
    const float* s = (which == 0) ? a : (which == 1) ? b : (which == 2) ? c : d;
    o[i] = __float2bfloat16(s[off]);
}

// ---------------------------------------------------------------------------
// WQF[c][c'] = Wq[c][c'] + sum_i Wffn[c][i] * Wq[i][c']   (f32 -> bf16)
// ---------------------------------------------------------------------------
__global__ __launch_bounds__(256) void wqf_kernel(
    const float* __restrict__ Wffn, const float* __restrict__ Wq,
    bf16* __restrict__ WQF)
{
    const int c = blockIdx.x, cp = threadIdx.x;
    float acc = Wq[c * 256 + cp];
#pragma unroll 8
    for (int i = 0; i < 256; ++i)
        acc += Wffn[c * 256 + i] * Wq[i * 256 + cp];
    WQF[c * 256 + cp] = __float2bfloat16(acc);
}

// ---------------------------------------------------------------------------
// Q projection (8 waves), fused transpose-convert; dual-writes xbf (s-major).
// qch[b][o][s] = sum_c Wq[o][c] x[b][c][s];  xbf[b][s][c] = bf16(x[b][c][s])
// grid (32 s-tiles, 16 b), block 512: waves (wm 0..3 -> 64 o, wn 0..1 -> 64 s)
// ---------------------------------------------------------------------------
__global__ __launch_bounds__(512) void qproj8(
    const float* __restrict__ x,   // [16][256][4096]
    const bf16* __restrict__ Wq,   // [256][256]
    bf16* __restrict__ qch,        // [16][256][4096]
    bf16* __restrict__ xbf)        // [16][4096][256]
{
    __shared__ bf16 sW[256 * 64];  // [o][64c] chunk-XOR swizzled
    __shared__ bf16 sX[128 * 72];  // [s][c], 144B rows
    const int t = threadIdx.x;
    const int lane = t & 63, wid = t >> 6;
    const int wm = wid >> 1, wn = wid & 1;
    const int g = lane >> 4, lr = lane & 15;
    const int s0 = blockIdx.x * 128;
    const int b = blockIdx.y;
    const float* xb = x + (long)b * 1048576;
    bf16* xob = xbf + (long)b * 1048576;

    f32x4 acc[4][4];
#pragma unroll
    for (int i = 0; i < 4; ++i)
#pragma unroll
        for (int j = 0; j < 4; ++j) acc[i][j] = (f32x4){0.f, 0.f, 0.f, 0.f};

    const int p  = t & 31;   // c-pair
    const int sl = t >> 5;   // 0..15

    for (int c0 = 0; c0 < 256; c0 += 64) {
        __syncthreads();
#pragma unroll
        for (int i = 0; i < 4; ++i) {
            int lin = i * 512 + t, r = lin >> 3, ch = lin & 7;
            gl_lds16(Wq + (long)r * 256 + c0 + ((ch ^ (r & 7)) << 3), &sW[lin * 8]);
        }
#pragma unroll
        for (int j = 0; j < 2; ++j) {
            int s4 = j * 16 + sl;   // 0..31
            const float* src = xb + (long)(c0 + 2 * p) * 4096 + s0 + s4 * 4;
            float4 a = *(const float4*)src;
            float4 bq = *(const float4*)(src + 4096);
            u32 w0 = pk2(a.x, bq.x), w1 = pk2(a.y, bq.y);
            u32 w2 = pk2(a.z, bq.z), w3 = pk2(a.w, bq.w);
            char* base = (char*)sX + p * 4 + (s4 * 4) * 144;
            *(u32*)(base +   0) = w0;
            *(u32*)(base + 144) = w1;
            *(u32*)(base + 288) = w2;
            *(u32*)(base + 432) = w3;
            long xo = (long)(s0 + s4 * 4) * 256 + c0 + 2 * p;
            *(u32*)(xob + xo)       = w0;
            *(u32*)(xob + xo + 256) = w1;
            *(u32*)(xob + xo + 512) = w2;
            *(u32*)(xob + xo + 768) = w3;
        }
        __syncthreads();
#pragma unroll
        for (int kk = 0; kk < 2; ++kk) {
            bf16x8 aw[4], fx[4];
#pragma unroll
            for (int mf = 0; mf < 4; ++mf) {
                int r = wm * 64 + mf * 16 + lr;
                aw[mf] = *(const bf16x8*)((const char*)sW + r * 128 + (((kk * 4 + g) ^ (r & 7)) << 4));
            }
#pragma unroll
            for (int nf = 0; nf < 4; ++nf) {
                int s = wn * 64 + nf * 16 + lr;
                fx[nf] = *(const bf16x8*)((const char*)sX + s * 144 + (kk * 4 + g) * 16);
            }
#pragma unroll
            for (int mf = 0; mf < 4; ++mf)
#pragma unroll
                for (int nf = 0; nf < 4; ++nf)
                    acc[mf][nf] = __builtin_amdgcn_mfma_f32_16x16x32_bf16(
                        aw[mf], fx[nf], acc[mf][nf], 0, 0, 0);
        }
    }
    bf16* qb = qch + (long)b * 1048576;
#pragma unroll
    for (int mf = 0; mf < 4; ++mf)
#pragma unroll
        for (int nf = 0; nf < 4; ++nf)
#pragma unroll
            for (int e = 0; e < 4; ++e) {
                int o = wm * 64 + mf * 16 + g * 4 + e;
                int s = s0 + wn * 64 + nf * 16 + lr;
                qb[(long)o * 4096 + s] = __float2bfloat16(acc[mf][nf][e]);
            }
}

// ---------------------------------------------------------------------------
// Fused K/V projection + QK^T partial + sumsq.  k never hits HBM.
// grid (8 s-chunks of 512, 64 bn), block 256 (4 waves).
// ---------------------------------------------------------------------------
__global__ __launch_bounds__(256) void kvqk(
    const float* __restrict__ fm,   // [64][256][4096]
    const bf16* __restrict__ Wk,    // [4][64][256]
    const bf16* __restrict__ Wv,    // [4][64][256]
    const bf16* __restrict__ qch,   // [16][256][4096]
    bf16* __restrict__ vT,          // [64][4096][64]
    float* __restrict__ part,       // [64][8][64][64]
    float* __restrict__ sums)       // [0:4096) sumq, [4096:8192) sumk
{
    __shared__ bf16 sF[128 * 72];   // fm tile [s][c], 144B rows
    __shared__ bf16 sWk[64 * 64];
    __shared__ bf16 sWv[64 * 64];
    __shared__ bf16 sKt[64 * 128];  // k [dd][s], XOR-swizzled
    __shared__ bf16 sQ[64 * 128];   // q-head [e][s], pre-swz source
    const int t = threadIdx.x;
    const int lane = t & 63, wid = t >> 6;
    const int g = lane >> 4, lr = lane & 15;
    const int ch_ = blockIdx.x;     // 0..7
    const int bn = blockIdx.y, n = bn & 3;
    const float* fb = fm + (long)bn * 1048576;
    const bf16* WkN = Wk + (long)n * 16384;
    const bf16* WvN = Wv + (long)n * 16384;
    const bf16* qbase = qch + (long)bn * 262144;
    bf16* vtb = vT + (long)bn * 262144;

    const int p  = t & 31;
    const int sl = t >> 5;
    const int srow = t >> 1, shalf = t & 1;

    f32x4 accQ[4];
#pragma unroll
    for (int i = 0; i < 4; ++i) accQ[i] = (f32x4){0.f, 0.f, 0.f, 0.f};
    float ssum = 0.f;

    for (int sub = 0; sub < 4; ++sub) {
        const int ss0 = ch_ * 512 + sub * 128;
        f32x4 acc1[4][2], acc2[2][4];
#pragma unroll
        for (int i = 0; i < 4; ++i)
#pragma unroll
            for (int j = 0; j < 2; ++j) {
                acc1[i][j] = (f32x4){0.f, 0.f, 0.f, 0.f};
                acc2[j][i] = (f32x4){0.f, 0.f, 0.f, 0.f};
            }

        for (int c0 = 0; c0 < 256; c0 += 64) {
            __syncthreads();
#pragma unroll
            for (int i = 0; i < 2; ++i) {
                int lin = i * 256 + t, r = lin >> 3, c = lin & 7;
                int off = r * 256 + c0 + ((c ^ (r & 7)) << 3);
                gl_lds16(WkN + off, &sWk[lin * 8]);
                gl_lds16(WvN + off, &sWv[lin * 8]);
            }
#pragma unroll
            for (int j = 0; j < 4; ++j) {
                int s4 = j * 8 + sl;
                const float* src = fb + (long)(c0 + 2 * p) * 4096 + ss0 + s4 * 4;
                float4 a = *(const float4*)src;
                float4 bq = *(const float4*)(src + 4096);
                char* base = (char*)sF + p * 4 + (s4 * 4) * 144;
                *(u32*)(base +   0) = pk2(a.x, bq.x);
                *(u32*)(base + 144) = pk2(a.y, bq.y);
                *(u32*)(base + 288) = pk2(a.z, bq.z);
                *(u32*)(base + 432) = pk2(a.w, bq.w);
            }
            __syncthreads();
#pragma unroll
            for (int kk = 0; kk < 2; ++kk) {
                bf16x8 ak[4], ff[2], bv[4];
#pragma unroll
                for (int mf = 0; mf < 4; ++mf) {
                    int r = mf * 16 + lr;
                    ak[mf] = *(const bf16x8*)((const char*)sWk + r * 128 + (((kk * 4 + g) ^ (r & 7)) << 4));
                }
#pragma unroll
                for (int i = 0; i < 2; ++i) {
                    int s = wid * 32 + i * 16 + lr;
                    ff[i] = *(const bf16x8*)((const char*)sF + s * 144 + (kk * 4 + g) * 16);
                }
#pragma unroll
                for (int nf = 0; nf < 4; ++nf) {
                    int r = nf * 16 + lr;
                    bv[nf] = *(const bf16x8*)((const char*)sWv + r * 128 + (((kk * 4 + g) ^ (r & 7)) << 4));
                }
#pragma unroll
                for (int mf = 0; mf < 4; ++mf)
#pragma unroll
                    for (int i = 0; i < 2; ++i)
                        acc1[mf][i] = __builtin_amdgcn_mfma_f32_16x16x32_bf16(
                            ak[mf], ff[i], acc1[mf][i], 0, 0, 0);
#pragma unroll
                for (int i = 0; i < 2; ++i)
#pragma unroll
                    for (int nf = 0; nf < 4; ++nf)
                        acc2[i][nf] = __builtin_amdgcn_mfma_f32_16x16x32_bf16(
                            ff[i], bv[nf], acc2[i][nf], 0, 0, 0);
            }
        }
        // stage q-head tile [64 e][128 s] (pre-swizzled source)
#pragma unroll
        for (int i = 0; i < 4; ++i) {
            int lin = i * 256 + t, r = lin >> 4, c = lin & 15;
            gl_lds16(qbase + (long)r * 4096 + ss0 + ((c ^ (r & 7)) << 3), &sQ[lin * 8]);
        }
        // v -> global
#pragma unroll
        for (int i = 0; i < 2; ++i)
#pragma unroll
            for (int nf = 0; nf < 4; ++nf)
#pragma unroll
                for (int e = 0; e < 4; ++e) {
                    int s = ss0 + wid * 32 + i * 16 + g * 4 + e;
                    vtb[(long)s * 64 + nf * 16 + lr] = __float2bfloat16(acc2[i][nf][e]);
                }
        // k -> sKt (swizzled u16 writes)
#pragma unroll
        for (int mf = 0; mf < 4; ++mf)
#pragma unroll
            for (int i = 0; i < 2; ++i)
#pragma unroll
                for (int e = 0; e < 4; ++e) {
                    int dd = mf * 16 + g * 4 + e;
                    int sc = wid * 32 + i * 16 + lr;
                    bf16 hv = __float2bfloat16(acc1[mf][i][e]);
                    int byte = (dd * 256 + sc * 2) ^ ((dd & 7) << 4);
                    *(u16*)((char*)sKt + byte) = *(u16*)&hv;
                }
        __syncthreads();
        // QK: wave wid owns dd rows [wid*16, wid*16+16)
#pragma unroll
        for (int kks = 0; kks < 4; ++kks) {
            int rA = wid * 16 + lr;
            bf16x8 af = *(const bf16x8*)((const char*)sKt + rA * 256 + (((kks * 4 + g) ^ (rA & 7)) << 4));
            bf16x8 bq[4];
#pragma unroll
            for (int nf = 0; nf < 4; ++nf) {
                int rB = nf * 16 + lr;
                bq[nf] = *(const bf16x8*)((const char*)sQ + rB * 256 + (((kks * 4 + g) ^ (rB & 7)) << 4));
            }
#pragma unroll
            for (int nf = 0; nf < 4; ++nf)
                accQ[nf] = __builtin_amdgcn_mfma_f32_16x16x32_bf16(
                    af, bq[nf], accQ[nf], 0, 0, 0);
        }
        // sumsq from LDS tiles (rows 0..63 = k, 64..127 = q)
        {
            const char* base = (srow < 64) ? (const char*)sKt + srow * 256
                                           : (const char*)sQ + (srow - 64) * 256;
            int r7 = srow & 7;
#pragma unroll
            for (int j = 0; j < 8; ++j) {
                bf16x8 v = *(const bf16x8*)(base + (((shalf * 8 + j) ^ r7) << 4));
#pragma unroll
                for (int e = 0; e < 8; ++e) {
                    float f = b2f((u16)v[e]);
                    ssum += f * f;
                }
            }
        }
    }
    // part write
    float* pp = part + ((long)bn * 8 + ch_) * 4096;
#pragma unroll
    for (int nf = 0; nf < 4; ++nf)
#pragma unroll
        for (int e = 0; e < 4; ++e) {
            int dd = wid * 16 + g * 4 + e;
            pp[dd * 64 + nf * 16 + lr] = accQ[nf][e];
        }
    // sums
    ssum += __shfl_xor(ssum, 1);
    if (shalf == 0) {
        if (srow < 64) atomicAdd(&sums[4096 + bn * 64 + srow], ssum);   // k
        else           atomicAdd(&sums[bn * 64 + (srow - 64)], ssum);   // q
    }
}

// ---------------------------------------------------------------------------
// finalize: sum partials, rsqrt norms, softmax, then M2 = Wffn_head @ P.
// grid 64 (bn), block 256.  M2[b][c][n*64+e] bf16.
// ---------------------------------------------------------------------------
__global__ __launch_bounds__(256) void finalizeM2(
    const float* __restrict__ part, const float* __restrict__ sums,
    const float* __restrict__ rescale, const bf16* __restrict__ Wf,
    bf16* __restrict__ M2)
{
    __shared__ float att[64][65];
    __shared__ float rmax[64], rsm[64], iq[64], ik[64];
    __shared__ bf16 sWf[256 * 64];
    __shared__ bf16 attT[64 * 64];  // [e][dd] swizzled
    const int bn = blockIdx.x, n = bn & 3, b = bn >> 2;
    const int t = threadIdx.x;
    const int lane = t & 63, wid = t >> 6;
    const int g = lane >> 4, lr = lane & 15;
    const float rs = rescale[n];

#pragma unroll
    for (int i = 0; i < 8; ++i) {
        int lin = i * 256 + t, r = lin >> 3, c = lin & 7;
        gl_lds16(Wf + (long)r * 256 + n * 64 + ((c ^ (r & 7)) << 3), &sWf[lin * 8]);
    }
    if (t < 64)        ik[t]      = 1.f / fmaxf(sqrtf(sums[4096 + bn * 64 + t]), 1e-12f);
    else if (t < 128)  iq[t - 64] = 1.f / fmaxf(sqrtf(sums[bn * 64 + t - 64]), 1e-12f);
    __syncthreads();

    const float* pb = part + (long)bn * 8 * 4096;
#pragma unroll
    for (int p_ = 0; p_ < 16; ++p_) {
        int lin = p_ * 256 + t;
        int dd = lin >> 6, e = lin & 63;
        float v = 0.f;
#pragma unroll
        for (int c = 0; c < 8; ++c) v += pb[c * 4096 + lin];
        att[dd][e] = v * ik[dd] * iq[e] * rs;
    }
    __syncthreads();
    if (t < 64) {
        float m = -1e30f;
        for (int e = 0; e < 64; ++e) m = fmaxf(m, att[t][e]);
        float sm = 0.f;
        for (int e = 0; e < 64; ++e) sm += expf(att[t][e] - m);
        rmax[t] = m;
        rsm[t] = 1.0f / sm;
    }
    __syncthreads();
#pragma unroll
    for (int p_ = 0; p_ < 16; ++p_) {
        int lin = p_ * 256 + t;
        int dd = lin >> 6, e = lin & 63;
        bf16 hv = __float2bfloat16(expf(att[dd][e] - rmax[dd]) * rsm[dd]);
        int byte = (e * 128 + dd * 2) ^ ((e & 7) << 4);
        *(u16*)((char*)attT + byte) = *(u16*)&hv;
    }
    __syncthreads();   // attT ready; sWf drained

    f32x4 acc[4][4];
#pragma unroll
    for (int i = 0; i < 4; ++i)
#pragma unroll
        for (int j = 0; j < 4; ++j) acc[i][j] = (f32x4){0.f, 0.f, 0.f, 0.f};
#pragma unroll
    for (int kk = 0; kk < 2; ++kk) {
        bf16x8 aw[4], bt[4];
#pragma unroll
        for (int mf = 0; mf < 4; ++mf) {
            int r = wid * 64 + mf * 16 + lr;
            aw[mf] = *(const bf16x8*)((const char*)sWf + r * 128 + (((kk * 4 + g) ^ (r & 7)) << 4));
        }
#pragma unroll
        for (int nf = 0; nf < 4; ++nf) {
            int e = nf * 16 + lr;
            bt[nf] = *(const bf16x8*)((const char*)attT + e * 128 + (((kk * 4 + g) ^ (e & 7)) << 4));
        }
#pragma unroll
        for (int mf = 0; mf < 4; ++mf)
#pragma unroll
            for (int nf = 0; nf < 4; ++nf)
                acc[mf][nf] = __builtin_amdgcn_mfma_f32_16x16x32_bf16(
                    aw[mf], bt[nf], acc[mf][nf], 0, 0, 0);
    }
    bf16* m2b = M2 + (long)b * 65536;
#pragma unroll
    for (int mf = 0; mf < 4; ++mf)
#pragma unroll
        for (int nf = 0; nf < 4; ++nf)
#pragma unroll
            for (int e = 0; e < 4; ++e) {
                int c = wid * 64 + mf * 16 + g * 4 + e;
                m2b[c * 256 + n * 64 + nf * 16 + lr] = __float2bfloat16(acc[mf][nf][e]);
            }
}

// ---------------------------------------------------------------------------
// out[b][c][s] = sum_e' M2[b][c][e'] v[b][e'][s] + sum_c' WQF[c][c'] x[c'][s]
//              + bffn[c]
// grid (32 s-tiles, 16 b), block 512 (wm 0..3 -> 64 c, wn 0..1 -> 64 s).
// ---------------------------------------------------------------------------
__global__ __launch_bounds__(512) void outgemm(
    const bf16* __restrict__ M2,   // [16][256][256]
    const bf16* __restrict__ WQF,  // [256][256]
    const bf16* __restrict__ vT,   // [64][4096][64]
    const bf16* __restrict__ xbf,  // [16][4096][256]
    const float* __restrict__ bffn,
    float* __restrict__ out)       // [16][256][4096]
{
    __shared__ bf16 sA[256 * 64];
    __shared__ bf16 sB[128 * 64];
    const int t = threadIdx.x;
    const int lane = t & 63, wid = t >> 6;
    const int wm = wid >> 1, wn = wid & 1;
    const int g = lane >> 4, lr = lane & 15;
    const int s0 = blockIdx.x * 128;
    const int b = blockIdx.y;

    f32x4 acc[4][4];
#pragma unroll
    for (int i = 0; i < 4; ++i)
#pragma unroll
        for (int j = 0; j < 4; ++j) acc[i][j] = (f32x4){0.f, 0.f, 0.f, 0.f};

    for (int ch = 0; ch < 8; ++ch) {
        const bf16* Asrc;
        const bf16* Bsrc;
        int Brs;
        if (ch < 4) {
            Asrc = M2 + (long)b * 65536 + ch * 64;
            Bsrc = vT + ((long)b * 4 + ch) * 262144 + (long)s0 * 64;
            Brs = 64;
        } else {
            Asrc = WQF + (ch - 4) * 64;
            Bsrc = xbf + (long)b * 1048576 + (long)s0 * 256 + (ch - 4) * 64;
            Brs = 256;
        }
        __syncthreads();
#pragma unroll
        for (int i = 0; i < 4; ++i) {
            int lin = i * 512 + t, r = lin >> 3, c = lin & 7;
            gl_lds16(Asrc + (long)r * 256 + ((c ^ (r & 7)) << 3), &sA[lin * 8]);
        }
#pragma unroll
        for (int i = 0; i < 2; ++i) {
            int lin = i * 512 + t, r = lin >> 3, c = lin & 7;
            gl_lds16(Bsrc + (long)r * Brs + ((c ^ (r & 7)) << 3), &sB[lin * 8]);
        }
        __syncthreads();
#pragma unroll
        for (int kk = 0; kk < 2; ++kk) {
            bf16x8 aw[4], bz[4];
#pragma unroll
            for (int mf = 0; mf < 4; ++mf) {
                int r = wm * 64 + mf * 16 + lr;
                aw[mf] = *(const bf16x8*)((const char*)sA + r * 128 + (((kk * 4 + g) ^ (r & 7)) << 4));
            }
#pragma unroll
            for (int nf = 0; nf < 4; ++nf) {
                int r = wn * 64 + nf * 16 + lr;
                bz[nf] = *(const bf16x8*)((const char*)sB + r * 128 + (((kk * 4 + g) ^ (r & 7)) << 4));
            }
#pragma unroll
            for (int mf = 0; mf < 4; ++mf)
#pragma unroll
                for (int nf = 0; nf < 4; ++nf)
                    acc[mf][nf] = __builtin_amdgcn_mfma_f32_16x16x32_bf16(
                        aw[mf], bz[nf], acc[mf][nf], 0, 0, 0);
        }
    }
    float* ob = out + (long)b * 1048576;
#pragma unroll
    for (int mf = 0; mf < 4; ++mf)
#pragma unroll
        for (int e = 0; e < 4; ++e) {
            int c = wm * 64 + mf * 16 + g * 4 + e;
            float bv = bffn[c];
#pragma unroll
            for (int nf = 0; nf < 4; ++nf) {
                int s = s0 + wn * 64 + nf * 16 + lr;
                ob[(long)c * 4096 + s] = acc[mf][nf][e] + bv;
            }
        }
}

// ---------------------------------------------------------------------------
extern "C" void kernel_launch(void* const* d_in, const int* in_sizes, int n_in,
                              void* d_out, int out_size, void* d_ws, size_t ws_size,
                              hipStream_t stream) {
    const float* x       = (const float*)d_in[0];
    const float* fmaps   = (const float*)d_in[1];
    const float* Wq      = (const float*)d_in[2];
    const float* Wk      = (const float*)d_in[3];
    const float* Wv      = (const float*)d_in[4];
    const float* rescale = (const float*)d_in[5];
    const float* Wffn    = (const float*)d_in[6];
    const float* bffn    = (const float*)d_in[7];
    float* out = (float*)d_out;

    char* w = (char*)d_ws;
    // layout (fixed: M2 is 2 MB, weights AFTER it)
    bf16* qch   = (bf16*)(w + 0);             //  33.55 MB
    bf16* vT    = (bf16*)(w + 33554432L);     //  33.55 MB
    bf16* xbf   = (bf16*)(w + 67108864L);     //  33.55 MB
    float* part = (float*)(w + 100663296L);   //   8.39 MB  (64*8*4096 f32)
    float* sums = (float*)(w + 109051904L);   //  32 KB
    bf16* M2    = (bf16*)(w + 109084672L);    //   2 MB (16*256*256 bf16)
    bf16* Wq_b  = (bf16*)(w + 111181824L);    // 4 x 128 KB
    bf16* Wk_b  = Wq_b + 65536;
    bf16* Wv_b  = Wq_b + 131072;
    bf16* Wf_b  = Wq_b + 196608;
    bf16* WQF   = (bf16*)(w + 111706112L);    // 128 KB

    dim3 blk(256);

    hipMemsetAsync(sums, 0, 32768, stream);
    // 1. weights -> bf16
    wconv<<<dim3(1024), blk, 0, stream>>>(Wq, Wk, Wv, Wffn, Wq_b);
    // 2. WQF = Wffn @ Wq + Wq
    wqf_kernel<<<dim3(256), blk, 0, stream>>>(Wffn, Wq, WQF);
    // 3. Q projection + xbf
    qproj8<<<dim3(32, 16), dim3(512), 0, stream>>>(x, Wq_b, qch, xbf);
    // 4. fused K/V proj + QK^T + sumsq
    kvqk<<<dim3(8, 64), blk, 0, stream>>>(fmaps, Wk_b, Wv_b, qch, vT, part, sums);
    // 5. softmax + M2
    finalizeM2<<<dim3(64), blk, 0, stream>>>(part, sums, rescale, Wf_b, M2);
    // 6. final fused GEMM
    outgemm<<<dim3(32, 16), dim3(512), 0, stream>>>(M2, WQF, vT, xbf, bffn, out);
}